// Round 1
// baseline (13233.482 us; speedup 1.0000x reference)
//
#include <hip/hip_runtime.h>
#include <math.h>

static constexpr float kNegSlope = 0.2f;
static constexpr float kEps = 1e-16f;

__device__ __forceinline__ float leaky(float v) {
    return v > 0.0f ? v : kNegSlope * v;
}

// Atomic float max via the signed/unsigned int trick. Canonicalize -0 -> +0
// so the (value >= 0) path never sees 0x80000000.
__device__ __forceinline__ void atomicMaxFloat(float* addr, float value) {
    value += 0.0f;
    if (value >= 0.0f) atomicMax((int*)addr, __float_as_int(value));
    else               atomicMin((unsigned int*)addr, __float_as_uint(value));
}

// ---------------- init ----------------
__global__ void k_init1(float* __restrict__ o1, float* __restrict__ m1,
                        float* __restrict__ s1, int n128, int n8) {
    int stride = gridDim.x * blockDim.x;
    int t0 = blockIdx.x * blockDim.x + threadIdx.x;
    for (int i = t0; i < n128; i += stride) o1[i] = 0.0f;
    for (int i = t0; i < n8; i += stride) { m1[i] = -INFINITY; s1[i] = 0.0f; }
}

__global__ void k_init2(float* __restrict__ m2, float* __restrict__ s2,
                        float* __restrict__ agg2, int n) {
    int stride = gridDim.x * blockDim.x;
    int t0 = blockIdx.x * blockDim.x + threadIdx.x;
    for (int i = t0; i < n; i += stride) { m2[i] = -INFINITY; s2[i] = 0.0f; }
    for (int i = t0; i < 4 * n; i += stride) agg2[i] = 0.0f;
}

// ---------------- layer 1 ----------------
// thread t -> (node n, head h). h1[n,128] = x[n,:2] @ W1[2,128]; fused att dots.
__global__ void k_transform1(const float* __restrict__ x, const float* __restrict__ W1,
                             const float* __restrict__ att_src, const float* __restrict__ att_dst,
                             float* __restrict__ h1, float* __restrict__ a1s,
                             float* __restrict__ a1d, int N) {
    int t = blockIdx.x * blockDim.x + threadIdx.x;
    if (t >= N * 8) return;
    int n = t >> 3, h = t & 7;
    float x0 = x[2 * n], x1 = x[2 * n + 1];
    float v[16];
    float as_ = 0.0f, ad_ = 0.0f;
#pragma unroll
    for (int c = 0; c < 16; ++c) {
        int col = h * 16 + c;
        float val = x0 * W1[col] + x1 * W1[128 + col];
        v[c] = val;
        as_ += val * att_src[col];
        ad_ += val * att_dst[col];
    }
    float4* hp = (float4*)(h1 + (size_t)n * 128 + h * 16);
    hp[0] = make_float4(v[0], v[1], v[2], v[3]);
    hp[1] = make_float4(v[4], v[5], v[6], v[7]);
    hp[2] = make_float4(v[8], v[9], v[10], v[11]);
    hp[3] = make_float4(v[12], v[13], v[14], v[15]);
    a1s[t] = as_;
    a1d[t] = ad_;
}

// thread per edge, all 8 heads: atomic max of leakyrelu(a_src[src]+a_dst[dst])
__global__ void k_edge_max1(const int* __restrict__ ei, const float* __restrict__ a1s,
                            const float* __restrict__ a1d, float* __restrict__ m1, int E) {
    int e = blockIdx.x * blockDim.x + threadIdx.x;
    if (e >= E) return;
    int s = ei[e], d = ei[E + e];
    const float4* sp = (const float4*)(a1s + (size_t)s * 8);
    const float4* dp = (const float4*)(a1d + (size_t)d * 8);
    float4 s0 = sp[0], s1v = sp[1], d0 = dp[0], d1v = dp[1];
    float* mp = m1 + (size_t)d * 8;
    atomicMaxFloat(mp + 0, leaky(s0.x + d0.x));
    atomicMaxFloat(mp + 1, leaky(s0.y + d0.y));
    atomicMaxFloat(mp + 2, leaky(s0.z + d0.z));
    atomicMaxFloat(mp + 3, leaky(s0.w + d0.w));
    atomicMaxFloat(mp + 4, leaky(s1v.x + d1v.x));
    atomicMaxFloat(mp + 5, leaky(s1v.y + d1v.y));
    atomicMaxFloat(mp + 6, leaky(s1v.z + d1v.z));
    atomicMaxFloat(mp + 7, leaky(s1v.w + d1v.w));
}

__global__ void k_edge_sum1(const int* __restrict__ ei, const float* __restrict__ a1s,
                            const float* __restrict__ a1d, const float* __restrict__ m1,
                            float* __restrict__ s1, int E) {
    int e = blockIdx.x * blockDim.x + threadIdx.x;
    if (e >= E) return;
    int s = ei[e], d = ei[E + e];
    const float4* sp = (const float4*)(a1s + (size_t)s * 8);
    const float4* dp = (const float4*)(a1d + (size_t)d * 8);
    const float4* mp = (const float4*)(m1 + (size_t)d * 8);
    float4 s0 = sp[0], s1v = sp[1], d0 = dp[0], d1v = dp[1];
    float4 m0 = mp[0], m1v = mp[1];
    float* op = s1 + (size_t)d * 8;
    atomicAdd(op + 0, expf(leaky(s0.x + d0.x) - m0.x));
    atomicAdd(op + 1, expf(leaky(s0.y + d0.y) - m0.y));
    atomicAdd(op + 2, expf(leaky(s0.z + d0.z) - m0.z));
    atomicAdd(op + 3, expf(leaky(s0.w + d0.w) - m0.w));
    atomicAdd(op + 4, expf(leaky(s1v.x + d1v.x) - m1v.x));
    atomicAdd(op + 5, expf(leaky(s1v.y + d1v.y) - m1v.y));
    atomicAdd(op + 6, expf(leaky(s1v.z + d1v.z) - m1v.z));
    atomicAdd(op + 7, expf(leaky(s1v.w + d1v.w) - m1v.w));
}

// thread per (edge, head): alpha-weighted scatter of h1[src, h, :16] into o1[dst, h, :16]
__global__ void k_edge_agg1(const int* __restrict__ ei, const float* __restrict__ a1s,
                            const float* __restrict__ a1d, const float* __restrict__ m1,
                            const float* __restrict__ s1, const float* __restrict__ h1,
                            float* __restrict__ o1, int E) {
    int t = blockIdx.x * blockDim.x + threadIdx.x;
    if (t >= E * 8) return;
    int e = t >> 3, h = t & 7;
    int s = ei[e], d = ei[E + e];
    float v = leaky(a1s[(size_t)s * 8 + h] + a1d[(size_t)d * 8 + h]);
    float alpha = expf(v - m1[(size_t)d * 8 + h]) / (s1[(size_t)d * 8 + h] + kEps);
    const float4* hp = (const float4*)(h1 + (size_t)s * 128 + h * 16);
    float* op = o1 + (size_t)d * 128 + h * 16;
#pragma unroll
    for (int k = 0; k < 4; ++k) {
        float4 hv = hp[k];
        atomicAdd(op + 4 * k + 0, hv.x * alpha);
        atomicAdd(op + 4 * k + 1, hv.y * alpha);
        atomicAdd(op + 4 * k + 2, hv.z * alpha);
        atomicAdd(op + 4 * k + 3, hv.w * alpha);
    }
}

__global__ void k_relu_bias1(float* __restrict__ o1, const float* __restrict__ b1, int n128) {
    int i = blockIdx.x * blockDim.x + threadIdx.x;
    if (i * 4 >= n128) return;
    float4* p = (float4*)o1 + i;
    const float4* bp = (const float4*)b1 + (i & 31);
    float4 v = *p, b = *bp;
    v.x = fmaxf(v.x + b.x, 0.0f);
    v.y = fmaxf(v.y + b.y, 0.0f);
    v.z = fmaxf(v.z + b.z, 0.0f);
    v.w = fmaxf(v.w + b.w, 0.0f);
    *p = v;
}

// ---------------- layer 2 ----------------
// thread per node: h2[n,:4] = o1[n,:128] @ W2[128,4]; fused att dots
__global__ void k_transform2(const float* __restrict__ o1, const float* __restrict__ W2,
                             const float* __restrict__ att_src, const float* __restrict__ att_dst,
                             float* __restrict__ h2, float* __restrict__ a2s,
                             float* __restrict__ a2d, int N) {
    int n = blockIdx.x * blockDim.x + threadIdx.x;
    if (n >= N) return;
    const float4* row = (const float4*)(o1 + (size_t)n * 128);
    const float4* W2v = (const float4*)W2;  // row c of W2 is 4 contiguous floats
    float4 acc = make_float4(0.f, 0.f, 0.f, 0.f);
#pragma unroll 8
    for (int c4 = 0; c4 < 32; ++c4) {
        float4 r = row[c4];
        float4 w0 = W2v[4 * c4 + 0], w1 = W2v[4 * c4 + 1];
        float4 w2 = W2v[4 * c4 + 2], w3 = W2v[4 * c4 + 3];
        acc.x += r.x * w0.x + r.y * w1.x + r.z * w2.x + r.w * w3.x;
        acc.y += r.x * w0.y + r.y * w1.y + r.z * w2.y + r.w * w3.y;
        acc.z += r.x * w0.z + r.y * w1.z + r.z * w2.z + r.w * w3.z;
        acc.w += r.x * w0.w + r.y * w1.w + r.z * w2.w + r.w * w3.w;
    }
    ((float4*)h2)[n] = acc;
    a2s[n] = acc.x * att_src[0] + acc.y * att_src[1] + acc.z * att_src[2] + acc.w * att_src[3];
    a2d[n] = acc.x * att_dst[0] + acc.y * att_dst[1] + acc.z * att_dst[2] + acc.w * att_dst[3];
}

__global__ void k_edge_max2(const int* __restrict__ ei, const float* __restrict__ a2s,
                            const float* __restrict__ a2d, float* __restrict__ m2, int E) {
    int e = blockIdx.x * blockDim.x + threadIdx.x;
    if (e >= E) return;
    int s = ei[e], d = ei[E + e];
    atomicMaxFloat(m2 + d, leaky(a2s[s] + a2d[d]));
}

__global__ void k_edge_sum2(const int* __restrict__ ei, const float* __restrict__ a2s,
                            const float* __restrict__ a2d, const float* __restrict__ m2,
                            float* __restrict__ s2, int E) {
    int e = blockIdx.x * blockDim.x + threadIdx.x;
    if (e >= E) return;
    int s = ei[e], d = ei[E + e];
    atomicAdd(s2 + d, expf(leaky(a2s[s] + a2d[d]) - m2[d]));
}

__global__ void k_edge_agg2(const int* __restrict__ ei, const float* __restrict__ a2s,
                            const float* __restrict__ a2d, const float* __restrict__ m2,
                            const float* __restrict__ s2, const float* __restrict__ h2,
                            float* __restrict__ agg2, int E) {
    int e = blockIdx.x * blockDim.x + threadIdx.x;
    if (e >= E) return;
    int s = ei[e], d = ei[E + e];
    float v = leaky(a2s[s] + a2d[d]);
    float alpha = expf(v - m2[d]) / (s2[d] + kEps);
    float4 hv = ((const float4*)h2)[s];
    float* op = agg2 + (size_t)d * 4;
    atomicAdd(op + 0, hv.x * alpha);
    atomicAdd(op + 1, hv.y * alpha);
    atomicAdd(op + 2, hv.z * alpha);
    atomicAdd(op + 3, hv.w * alpha);
}

__global__ void k_logsoftmax(const float* __restrict__ agg2, const float* __restrict__ b2,
                             float* __restrict__ out, int N) {
    int n = blockIdx.x * blockDim.x + threadIdx.x;
    if (n >= N) return;
    float4 v = ((const float4*)agg2)[n];
    v.x += b2[0]; v.y += b2[1]; v.z += b2[2]; v.w += b2[3];
    float m = fmaxf(fmaxf(v.x, v.y), fmaxf(v.z, v.w));
    float sum = expf(v.x - m) + expf(v.y - m) + expf(v.z - m) + expf(v.w - m);
    float lse = m + logf(sum);
    ((float4*)out)[n] = make_float4(v.x - lse, v.y - lse, v.z - lse, v.w - lse);
}

extern "C" void kernel_launch(void* const* d_in, const int* in_sizes, int n_in,
                              void* d_out, int out_size, void* d_ws, size_t ws_size,
                              hipStream_t stream) {
    const float* x        = (const float*)d_in[0];
    const int*   ei       = (const int*)d_in[1];
    const float* W1       = (const float*)d_in[2];
    const float* att_src1 = (const float*)d_in[3];
    const float* att_dst1 = (const float*)d_in[4];
    const float* b1       = (const float*)d_in[5];
    const float* W2       = (const float*)d_in[6];
    const float* att_src2 = (const float*)d_in[7];
    const float* att_dst2 = (const float*)d_in[8];
    const float* b2       = (const float*)d_in[9];

    const int N = in_sizes[0] / 2;   // x is [N,2]
    const int E = in_sizes[1] / 2;   // edge_index is [2,E]

    // workspace layout (floats)
    float* base = (float*)d_ws;
    float* o1  = base;                       // N*128 (layer-1 output / accumulator)
    float* h1  = o1 + (size_t)N * 128;       // N*128 (dies after k_edge_agg1)
    float* a1s = h1 + (size_t)N * 128;       // N*8
    float* a1d = a1s + (size_t)N * 8;        // N*8
    float* m1  = a1d + (size_t)N * 8;        // N*8
    float* s1  = m1 + (size_t)N * 8;         // N*8
    // layer-2 buffers overlay the (dead) h1 region
    float* h2   = h1;                        // N*4
    float* a2s  = h2 + (size_t)N * 4;        // N
    float* a2d  = a2s + N;                   // N
    float* m2   = a2d + N;                   // N
    float* s2   = m2 + N;                    // N
    float* agg2 = s2 + N;                    // N*4

    const int T = 256;

    k_init1<<<2048, T, 0, stream>>>(o1, m1, s1, N * 128, N * 8);
    k_transform1<<<(N * 8 + T - 1) / T, T, 0, stream>>>(x, W1, att_src1, att_dst1, h1, a1s, a1d, N);
    k_edge_max1<<<(E + T - 1) / T, T, 0, stream>>>(ei, a1s, a1d, m1, E);
    k_edge_sum1<<<(E + T - 1) / T, T, 0, stream>>>(ei, a1s, a1d, m1, s1, E);
    k_edge_agg1<<<(E * 8 + T - 1) / T, T, 0, stream>>>(ei, a1s, a1d, m1, s1, h1, o1, E);
    k_relu_bias1<<<(N * 32 + T - 1) / T, T, 0, stream>>>(o1, b1, N * 128);
    k_init2<<<1024, T, 0, stream>>>(m2, s2, agg2, N);
    k_transform2<<<(N + T - 1) / T, T, 0, stream>>>(o1, W2, att_src2, att_dst2, h2, a2s, a2d, N);
    k_edge_max2<<<(E + T - 1) / T, T, 0, stream>>>(ei, a2s, a2d, m2, E);
    k_edge_sum2<<<(E + T - 1) / T, T, 0, stream>>>(ei, a2s, a2d, m2, s2, E);
    k_edge_agg2<<<(E + T - 1) / T, T, 0, stream>>>(ei, a2s, a2d, m2, s2, h2, agg2, E);
    k_logsoftmax<<<(N + T - 1) / T, T, 0, stream>>>(agg2, b2, (float*)d_out, N);
}

// Round 2
// 726.962 us; speedup vs baseline: 18.2038x; 18.2038x over previous
//
#include <hip/hip_runtime.h>
#include <math.h>

static constexpr float kNegSlope = 0.2f;
static constexpr float kEps = 1e-16f;

__device__ __forceinline__ float leaky(float v) {
    return v > 0.0f ? v : kNegSlope * v;
}

// ---------------- CSR build ----------------
__global__ void k_zero(int* __restrict__ deg, int N) {
    int stride = gridDim.x * blockDim.x;
    for (int i = blockIdx.x * blockDim.x + threadIdx.x; i < N; i += stride) deg[i] = 0;
}

__global__ void k_hist(const int* __restrict__ ei, int* __restrict__ deg, int E) {
    int e = blockIdx.x * blockDim.x + threadIdx.x;
    if (e >= E) return;
    atomicAdd(&deg[ei[E + e]], 1);
}

// single-block exclusive scan over deg[N] -> rowptr[N+1], cursor[N]
__global__ void k_scan(const int* __restrict__ deg, int* __restrict__ rowptr,
                       int* __restrict__ cursor, int N, int E) {
    __shared__ int sm[1024];
    int t = threadIdx.x;
    int chunk = (N + 1023) >> 10;
    int lo = t * chunk, hi = min(lo + chunk, N);
    int s = 0;
    for (int i = lo; i < hi; ++i) s += deg[i];
    sm[t] = s;
    __syncthreads();
    int own = s;
    for (int off = 1; off < 1024; off <<= 1) {
        int v = (t >= off) ? sm[t - off] : 0;
        __syncthreads();
        sm[t] += v;
        __syncthreads();
    }
    int run = sm[t] - own;  // exclusive prefix
    for (int i = lo; i < hi; ++i) {
        rowptr[i] = run;
        cursor[i] = run;
        run += deg[i];
    }
    if (t == 0) rowptr[N] = E;
}

__global__ void k_scatter(const int* __restrict__ ei, int* __restrict__ cursor,
                          int* __restrict__ ssrc, int E) {
    int e = blockIdx.x * blockDim.x + threadIdx.x;
    if (e >= E) return;
    int s = ei[e], d = ei[E + e];
    int pos = atomicAdd(&cursor[d], 1);
    ssrc[pos] = s;
}

// ---------------- layer 1 ----------------
// thread t -> (node n, head h). h1[n,128] = x[n,:2] @ W1[2,128]; fused att dots.
__global__ void k_transform1(const float* __restrict__ x, const float* __restrict__ W1,
                             const float* __restrict__ att_src, const float* __restrict__ att_dst,
                             float* __restrict__ h1, float* __restrict__ a1s,
                             float* __restrict__ a1d, int N) {
    int t = blockIdx.x * blockDim.x + threadIdx.x;
    if (t >= N * 8) return;
    int n = t >> 3, h = t & 7;
    float x0 = x[2 * n], x1 = x[2 * n + 1];
    float v[16];
    float as_ = 0.0f, ad_ = 0.0f;
#pragma unroll
    for (int c = 0; c < 16; ++c) {
        int col = h * 16 + c;
        float val = x0 * W1[col] + x1 * W1[128 + col];
        v[c] = val;
        as_ += val * att_src[col];
        ad_ += val * att_dst[col];
    }
    float4* hp = (float4*)(h1 + (size_t)n * 128 + h * 16);
    hp[0] = make_float4(v[0], v[1], v[2], v[3]);
    hp[1] = make_float4(v[4], v[5], v[6], v[7]);
    hp[2] = make_float4(v[8], v[9], v[10], v[11]);
    hp[3] = make_float4(v[12], v[13], v[14], v[15]);
    a1s[t] = as_;
    a1d[t] = ad_;
}

// one 128-thread block per dst node; thread = (head h = t>>4, channel c = t&15).
// Online softmax over incoming edges; no atomics.
__global__ void k_gather1(const int* __restrict__ rowptr, const int* __restrict__ ssrc,
                          const float* __restrict__ a1s, const float* __restrict__ a1d,
                          const float* __restrict__ h1, float* __restrict__ o1, int N) {
    int node = blockIdx.x;
    int t = threadIdx.x;
    int h = t >> 4;
    int start = rowptr[node], end = rowptr[node + 1];
    float ad = a1d[(size_t)node * 8 + h];
    float m = -INFINITY, l = 0.0f, acc = 0.0f;
    __shared__ int s_src[128];
    for (int j0 = start; j0 < end; j0 += 128) {
        int nj = min(128, end - j0);
        if (t < nj) s_src[t] = ssrc[j0 + t];
        __syncthreads();
        for (int jj = 0; jj < nj; ++jj) {
            int src = s_src[jj];
            float e = leaky(a1s[(size_t)src * 8 + h] + ad);
            float hv = h1[(size_t)src * 128 + t];
            if (e > m) {
                float sc = __expf(m - e);  // m=-inf -> 0
                acc *= sc;
                l *= sc;
                m = e;
            }
            float p = __expf(e - m);
            l += p;
            acc += p * hv;
        }
        __syncthreads();
    }
    o1[(size_t)node * 128 + t] = acc / (l + kEps);
}

__global__ void k_relu_bias1(float* __restrict__ o1, const float* __restrict__ b1, int n128) {
    int i = blockIdx.x * blockDim.x + threadIdx.x;
    if (i * 4 >= n128) return;
    float4* p = (float4*)o1 + i;
    const float4* bp = (const float4*)b1 + (i & 31);
    float4 v = *p, b = *bp;
    v.x = fmaxf(v.x + b.x, 0.0f);
    v.y = fmaxf(v.y + b.y, 0.0f);
    v.z = fmaxf(v.z + b.z, 0.0f);
    v.w = fmaxf(v.w + b.w, 0.0f);
    *p = v;
}

// ---------------- layer 2 ----------------
__global__ void k_transform2(const float* __restrict__ o1, const float* __restrict__ W2,
                             const float* __restrict__ att_src, const float* __restrict__ att_dst,
                             float* __restrict__ h2, float* __restrict__ a2s,
                             float* __restrict__ a2d, int N) {
    int n = blockIdx.x * blockDim.x + threadIdx.x;
    if (n >= N) return;
    const float4* row = (const float4*)(o1 + (size_t)n * 128);
    const float4* W2v = (const float4*)W2;  // row c of W2 is 4 contiguous floats
    float4 acc = make_float4(0.f, 0.f, 0.f, 0.f);
#pragma unroll 8
    for (int c4 = 0; c4 < 32; ++c4) {
        float4 r = row[c4];
        float4 w0 = W2v[4 * c4 + 0], w1 = W2v[4 * c4 + 1];
        float4 w2 = W2v[4 * c4 + 2], w3 = W2v[4 * c4 + 3];
        acc.x += r.x * w0.x + r.y * w1.x + r.z * w2.x + r.w * w3.x;
        acc.y += r.x * w0.y + r.y * w1.y + r.z * w2.y + r.w * w3.y;
        acc.z += r.x * w0.z + r.y * w1.z + r.z * w2.z + r.w * w3.z;
        acc.w += r.x * w0.w + r.y * w1.w + r.z * w2.w + r.w * w3.w;
    }
    ((float4*)h2)[n] = acc;
    a2s[n] = acc.x * att_src[0] + acc.y * att_src[1] + acc.z * att_src[2] + acc.w * att_src[3];
    a2d[n] = acc.x * att_dst[0] + acc.y * att_dst[1] + acc.z * att_dst[2] + acc.w * att_dst[3];
}

// thread per node: gather + online softmax + bias + log_softmax, writes d_out
__global__ void k_gather2_out(const int* __restrict__ rowptr, const int* __restrict__ ssrc,
                              const float* __restrict__ a2s, const float* __restrict__ a2d,
                              const float* __restrict__ h2, const float* __restrict__ b2,
                              float* __restrict__ out, int N) {
    int n = blockIdx.x * blockDim.x + threadIdx.x;
    if (n >= N) return;
    int start = rowptr[n], end = rowptr[n + 1];
    float ad = a2d[n];
    float m = -INFINITY, l = 0.0f;
    float4 acc = make_float4(0.f, 0.f, 0.f, 0.f);
    for (int j = start; j < end; ++j) {
        int src = ssrc[j];
        float e = leaky(a2s[src] + ad);
        float4 hv = ((const float4*)h2)[src];
        if (e > m) {
            float sc = __expf(m - e);
            acc.x *= sc; acc.y *= sc; acc.z *= sc; acc.w *= sc;
            l *= sc;
            m = e;
        }
        float p = __expf(e - m);
        l += p;
        acc.x += p * hv.x; acc.y += p * hv.y; acc.z += p * hv.z; acc.w += p * hv.w;
    }
    float inv = 1.0f / (l + kEps);
    float4 v = make_float4(acc.x * inv + b2[0], acc.y * inv + b2[1],
                           acc.z * inv + b2[2], acc.w * inv + b2[3]);
    float mx = fmaxf(fmaxf(v.x, v.y), fmaxf(v.z, v.w));
    float sum = __expf(v.x - mx) + __expf(v.y - mx) + __expf(v.z - mx) + __expf(v.w - mx);
    float lse = mx + logf(sum);
    ((float4*)out)[n] = make_float4(v.x - lse, v.y - lse, v.z - lse, v.w - lse);
}

extern "C" void kernel_launch(void* const* d_in, const int* in_sizes, int n_in,
                              void* d_out, int out_size, void* d_ws, size_t ws_size,
                              hipStream_t stream) {
    const float* x        = (const float*)d_in[0];
    const int*   ei       = (const int*)d_in[1];
    const float* W1       = (const float*)d_in[2];
    const float* att_src1 = (const float*)d_in[3];
    const float* att_dst1 = (const float*)d_in[4];
    const float* b1       = (const float*)d_in[5];
    const float* W2       = (const float*)d_in[6];
    const float* att_src2 = (const float*)d_in[7];
    const float* att_dst2 = (const float*)d_in[8];
    const float* b2       = (const float*)d_in[9];

    const int N = in_sizes[0] / 2;   // x is [N,2]
    const int E = in_sizes[1] / 2;   // edge_index is [2,E]

    // ---- workspace layout ----
    // ints first (N and E are multiples of 4, so 16B alignment is preserved)
    int* deg      = (int*)d_ws;                 // N (doubles as cursor)
    int* rowptr   = deg + N;                    // N+1 (padded to N+4)
    int* ssrc     = rowptr + N + 4;             // E
    float* fbase  = (float*)(ssrc + E);
    float* h1  = fbase;                         // N*128
    float* o1  = h1 + (size_t)N * 128;          // N*128
    float* a1s = o1 + (size_t)N * 128;          // N*8
    float* a1d = a1s + (size_t)N * 8;           // N*8
    // layer-2 buffers overlay the (dead) h1 region
    float* h2  = h1;                            // N*4
    float* a2s = h2 + (size_t)N * 4;            // N
    float* a2d = a2s + N;                       // N

    const int T = 256;

    // CSR build (by destination)
    k_zero<<<256, T, 0, stream>>>(deg, N);
    k_hist<<<(E + T - 1) / T, T, 0, stream>>>(ei, deg, E);
    k_scan<<<1, 1024, 0, stream>>>(deg, rowptr, deg /*cursor*/, N, E);
    k_scatter<<<(E + T - 1) / T, T, 0, stream>>>(ei, deg /*cursor*/, ssrc, E);

    // layer 1
    k_transform1<<<(N * 8 + T - 1) / T, T, 0, stream>>>(x, W1, att_src1, att_dst1, h1, a1s, a1d, N);
    k_gather1<<<N, 128, 0, stream>>>(rowptr, ssrc, a1s, a1d, h1, o1, N);
    k_relu_bias1<<<(N * 32 + T - 1) / T, T, 0, stream>>>(o1, b1, N * 128);

    // layer 2
    k_transform2<<<(N + T - 1) / T, T, 0, stream>>>(o1, W2, att_src2, att_dst2, h2, a2s, a2d, N);
    k_gather2_out<<<(N + T - 1) / T, T, 0, stream>>>(rowptr, ssrc, a2s, a2d, h2, b2, (float*)d_out, N);
}

// Round 3
// 498.575 us; speedup vs baseline: 26.5426x; 1.4581x over previous
//
#include <hip/hip_runtime.h>
#include <math.h>

static constexpr float kNegSlope = 0.2f;
static constexpr float kEps = 1e-16f;

__device__ __forceinline__ float leaky(float v) {
    return v > 0.0f ? v : kNegSlope * v;
}

// ---------------- CSR build ----------------
__global__ void k_zero(int* __restrict__ deg, int N) {
    int stride = gridDim.x * blockDim.x;
    for (int i = blockIdx.x * blockDim.x + threadIdx.x; i < N; i += stride) deg[i] = 0;
}

__global__ void k_hist(const int* __restrict__ ei, int* __restrict__ deg, int E) {
    int e = blockIdx.x * blockDim.x + threadIdx.x;
    if (e >= E) return;
    atomicAdd(&deg[ei[E + e]], 1);
}

// Phase A: block b tree-reduces deg[b*1024 .. b*1024+1023] -> partial[b]
__global__ void k_scan_reduce(const int* __restrict__ deg, int* __restrict__ partial, int N) {
    __shared__ int sm[1024];
    int t = threadIdx.x;
    int i = blockIdx.x * 1024 + t;
    sm[t] = (i < N) ? deg[i] : 0;
    __syncthreads();
#pragma unroll
    for (int off = 512; off > 0; off >>= 1) {
        if (t < off) sm[t] += sm[t + off];
        __syncthreads();
    }
    if (t == 0) partial[blockIdx.x] = sm[0];
}

// Phase B: one block converts partial[NB] to its exclusive scan in-place; also rowptr[N]=E
__global__ void k_scan_top(int* __restrict__ partial, int* __restrict__ rowptr,
                           int NB, int N, int E) {
    __shared__ int sm[1024];
    int t = threadIdx.x;
    int v = (t < NB) ? partial[t] : 0;
    sm[t] = v;
    __syncthreads();
    for (int off = 1; off < 1024; off <<= 1) {
        int u = (t >= off) ? sm[t - off] : 0;
        __syncthreads();
        sm[t] += u;
        __syncthreads();
    }
    if (t < NB) partial[t] = sm[t] - v;  // exclusive
    if (t == 0) rowptr[N] = E;
}

// Phase C: block b scans its 1024-chunk in LDS, adds partial[b], writes rowptr+cursor
__global__ void k_scan_final(const int* __restrict__ deg, const int* __restrict__ partial,
                             int* __restrict__ rowptr, int* __restrict__ cursor, int N) {
    __shared__ int sm[1024];
    int t = threadIdx.x;
    int i = blockIdx.x * 1024 + t;
    int v = (i < N) ? deg[i] : 0;
    sm[t] = v;
    __syncthreads();
    for (int off = 1; off < 1024; off <<= 1) {
        int u = (t >= off) ? sm[t - off] : 0;
        __syncthreads();
        sm[t] += u;
        __syncthreads();
    }
    if (i < N) {
        int excl = sm[t] - v + partial[blockIdx.x];
        rowptr[i] = excl;
        cursor[i] = excl;
    }
}

__global__ void k_scatter(const int* __restrict__ ei, int* __restrict__ cursor,
                          int* __restrict__ ssrc, int E) {
    int e = blockIdx.x * blockDim.x + threadIdx.x;
    if (e >= E) return;
    int s = ei[e], d = ei[E + e];
    int pos = atomicAdd(&cursor[d], 1);
    ssrc[pos] = s;
}

// ---------------- layer 1 ----------------
// thread t -> (node n, head h). h1[n,128] = x[n,:2] @ W1[2,128]; fused att dots.
__global__ void k_transform1(const float* __restrict__ x, const float* __restrict__ W1,
                             const float* __restrict__ att_src, const float* __restrict__ att_dst,
                             float* __restrict__ h1, float* __restrict__ a1s,
                             float* __restrict__ a1d, int N) {
    int t = blockIdx.x * blockDim.x + threadIdx.x;
    if (t >= N * 8) return;
    int n = t >> 3, h = t & 7;
    float x0 = x[2 * n], x1 = x[2 * n + 1];
    float v[16];
    float as_ = 0.0f, ad_ = 0.0f;
#pragma unroll
    for (int c = 0; c < 16; ++c) {
        int col = h * 16 + c;
        float val = x0 * W1[col] + x1 * W1[128 + col];
        v[c] = val;
        as_ += val * att_src[col];
        ad_ += val * att_dst[col];
    }
    float4* hp = (float4*)(h1 + (size_t)n * 128 + h * 16);
    hp[0] = make_float4(v[0], v[1], v[2], v[3]);
    hp[1] = make_float4(v[4], v[5], v[6], v[7]);
    hp[2] = make_float4(v[8], v[9], v[10], v[11]);
    hp[3] = make_float4(v[12], v[13], v[14], v[15]);
    a1s[t] = as_;
    a1d[t] = ad_;
}

// one 128-thread block per dst node; thread = (head h = t>>4, channel c = t&15).
// Online softmax over incoming edges; no atomics. Fused bias+ReLU epilogue.
__global__ void k_gather1(const int* __restrict__ rowptr, const int* __restrict__ ssrc,
                          const float* __restrict__ a1s, const float* __restrict__ a1d,
                          const float* __restrict__ h1, const float* __restrict__ b1,
                          float* __restrict__ o1, int N) {
    int node = blockIdx.x;
    int t = threadIdx.x;
    int h = t >> 4;
    int start = rowptr[node], end = rowptr[node + 1];
    float ad = a1d[(size_t)node * 8 + h];
    float m = -INFINITY, l = 0.0f, acc = 0.0f;
    __shared__ int s_src[128];
    for (int j0 = start; j0 < end; j0 += 128) {
        int nj = min(128, end - j0);
        if (t < nj) s_src[t] = ssrc[j0 + t];
        __syncthreads();
        for (int jj = 0; jj < nj; ++jj) {
            int src = s_src[jj];
            float e = leaky(a1s[(size_t)src * 8 + h] + ad);
            float hv = h1[(size_t)src * 128 + t];
            if (e > m) {
                float sc = __expf(m - e);  // m=-inf -> 0
                acc *= sc;
                l *= sc;
                m = e;
            }
            float p = __expf(e - m);
            l += p;
            acc += p * hv;
        }
        __syncthreads();
    }
    o1[(size_t)node * 128 + t] = fmaxf(acc / (l + kEps) + b1[t], 0.0f);
}

// ---------------- layer 2 ----------------
__global__ void k_transform2(const float* __restrict__ o1, const float* __restrict__ W2,
                             const float* __restrict__ att_src, const float* __restrict__ att_dst,
                             float* __restrict__ h2, float* __restrict__ a2s,
                             float* __restrict__ a2d, int N) {
    int n = blockIdx.x * blockDim.x + threadIdx.x;
    if (n >= N) return;
    const float4* row = (const float4*)(o1 + (size_t)n * 128);
    const float4* W2v = (const float4*)W2;  // row c of W2 is 4 contiguous floats
    float4 acc = make_float4(0.f, 0.f, 0.f, 0.f);
#pragma unroll 8
    for (int c4 = 0; c4 < 32; ++c4) {
        float4 r = row[c4];
        float4 w0 = W2v[4 * c4 + 0], w1 = W2v[4 * c4 + 1];
        float4 w2 = W2v[4 * c4 + 2], w3 = W2v[4 * c4 + 3];
        acc.x += r.x * w0.x + r.y * w1.x + r.z * w2.x + r.w * w3.x;
        acc.y += r.x * w0.y + r.y * w1.y + r.z * w2.y + r.w * w3.y;
        acc.z += r.x * w0.z + r.y * w1.z + r.z * w2.z + r.w * w3.z;
        acc.w += r.x * w0.w + r.y * w1.w + r.z * w2.w + r.w * w3.w;
    }
    ((float4*)h2)[n] = acc;
    a2s[n] = acc.x * att_src[0] + acc.y * att_src[1] + acc.z * att_src[2] + acc.w * att_src[3];
    a2d[n] = acc.x * att_dst[0] + acc.y * att_dst[1] + acc.z * att_dst[2] + acc.w * att_dst[3];
}

// thread per node: gather + online softmax + bias + log_softmax, writes d_out
__global__ void k_gather2_out(const int* __restrict__ rowptr, const int* __restrict__ ssrc,
                              const float* __restrict__ a2s, const float* __restrict__ a2d,
                              const float* __restrict__ h2, const float* __restrict__ b2,
                              float* __restrict__ out, int N) {
    int n = blockIdx.x * blockDim.x + threadIdx.x;
    if (n >= N) return;
    int start = rowptr[n], end = rowptr[n + 1];
    float ad = a2d[n];
    float m = -INFINITY, l = 0.0f;
    float4 acc = make_float4(0.f, 0.f, 0.f, 0.f);
    for (int j = start; j < end; ++j) {
        int src = ssrc[j];
        float e = leaky(a2s[src] + ad);
        float4 hv = ((const float4*)h2)[src];
        if (e > m) {
            float sc = __expf(m - e);
            acc.x *= sc; acc.y *= sc; acc.z *= sc; acc.w *= sc;
            l *= sc;
            m = e;
        }
        float p = __expf(e - m);
        l += p;
        acc.x += p * hv.x; acc.y += p * hv.y; acc.z += p * hv.z; acc.w += p * hv.w;
    }
    float inv = 1.0f / (l + kEps);
    float4 v = make_float4(acc.x * inv + b2[0], acc.y * inv + b2[1],
                           acc.z * inv + b2[2], acc.w * inv + b2[3]);
    float mx = fmaxf(fmaxf(v.x, v.y), fmaxf(v.z, v.w));
    float sum = __expf(v.x - mx) + __expf(v.y - mx) + __expf(v.z - mx) + __expf(v.w - mx);
    float lse = mx + logf(sum);
    ((float4*)out)[n] = make_float4(v.x - lse, v.y - lse, v.z - lse, v.w - lse);
}

extern "C" void kernel_launch(void* const* d_in, const int* in_sizes, int n_in,
                              void* d_out, int out_size, void* d_ws, size_t ws_size,
                              hipStream_t stream) {
    const float* x        = (const float*)d_in[0];
    const int*   ei       = (const int*)d_in[1];
    const float* W1       = (const float*)d_in[2];
    const float* att_src1 = (const float*)d_in[3];
    const float* att_dst1 = (const float*)d_in[4];
    const float* b1       = (const float*)d_in[5];
    const float* W2       = (const float*)d_in[6];
    const float* att_src2 = (const float*)d_in[7];
    const float* att_dst2 = (const float*)d_in[8];
    const float* b2       = (const float*)d_in[9];

    const int N = in_sizes[0] / 2;   // x is [N,2]
    const int E = in_sizes[1] / 2;   // edge_index is [2,E]
    const int NB = (N + 1023) / 1024;  // scan blocks (must be <= 1024)

    // ---- workspace layout ----
    int* deg      = (int*)d_ws;                 // N (doubles as cursor)
    int* rowptr   = deg + N;                    // N+1 (padded to N+4)
    int* ssrc     = rowptr + N + 4;             // E
    int* partial  = ssrc + E;                   // NB (pad 1024)
    float* fbase  = (float*)(partial + 1024);
    float* h1  = fbase;                         // N*128
    float* o1  = h1 + (size_t)N * 128;          // N*128
    float* a1s = o1 + (size_t)N * 128;          // N*8
    float* a1d = a1s + (size_t)N * 8;           // N*8
    // layer-2 buffers overlay the (dead) h1 region
    float* h2  = h1;                            // N*4
    float* a2s = h2 + (size_t)N * 4;            // N
    float* a2d = a2s + N;                       // N

    const int T = 256;

    // CSR build (by destination)
    k_zero<<<256, T, 0, stream>>>(deg, N);
    k_hist<<<(E + T - 1) / T, T, 0, stream>>>(ei, deg, E);
    k_scan_reduce<<<NB, 1024, 0, stream>>>(deg, partial, N);
    k_scan_top<<<1, 1024, 0, stream>>>(partial, rowptr, NB, N, E);
    k_scan_final<<<NB, 1024, 0, stream>>>(deg, partial, rowptr, deg /*cursor*/, N);
    k_scatter<<<(E + T - 1) / T, T, 0, stream>>>(ei, deg /*cursor*/, ssrc, E);

    // layer 1
    k_transform1<<<(N * 8 + T - 1) / T, T, 0, stream>>>(x, W1, att_src1, att_dst1, h1, a1s, a1d, N);
    k_gather1<<<N, 128, 0, stream>>>(rowptr, ssrc, a1s, a1d, h1, b1, o1, N);

    // layer 2
    k_transform2<<<(N + T - 1) / T, T, 0, stream>>>(o1, W2, att_src2, att_dst2, h2, a2s, a2d, N);
    k_gather2_out<<<(N + T - 1) / T, T, 0, stream>>>(rowptr, ssrc, a2s, a2d, h2, b2, (float*)d_out, N);
}

// Round 4
// 353.553 us; speedup vs baseline: 37.4300x; 1.4102x over previous
//
#include <hip/hip_runtime.h>
#include <math.h>

static constexpr float kNegSlope = 0.2f;
static constexpr float kEps = 1e-16f;

__device__ __forceinline__ float leaky(float v) {
    return v > 0.0f ? v : kNegSlope * v;
}

// ---------------- CSR build ----------------
__global__ void k_zero(int* __restrict__ deg, int N) {
    int stride = gridDim.x * blockDim.x;
    for (int i = blockIdx.x * blockDim.x + threadIdx.x; i < N; i += stride) deg[i] = 0;
}

__global__ void k_hist(const int* __restrict__ ei, int* __restrict__ deg, int E) {
    int e = blockIdx.x * blockDim.x + threadIdx.x;
    if (e >= E) return;
    atomicAdd(&deg[ei[E + e]], 1);
}

// Phase A: block b tree-reduces deg[b*1024 .. b*1024+1023] -> partial[b]
__global__ void k_scan_reduce(const int* __restrict__ deg, int* __restrict__ partial, int N) {
    __shared__ int sm[1024];
    int t = threadIdx.x;
    int i = blockIdx.x * 1024 + t;
    sm[t] = (i < N) ? deg[i] : 0;
    __syncthreads();
#pragma unroll
    for (int off = 512; off > 0; off >>= 1) {
        if (t < off) sm[t] += sm[t + off];
        __syncthreads();
    }
    if (t == 0) partial[blockIdx.x] = sm[0];
}

// Phase B: one block converts partial[NB] to exclusive scan in-place; rowptr[N]=E
__global__ void k_scan_top(int* __restrict__ partial, int* __restrict__ rowptr,
                           int NB, int N, int E) {
    __shared__ int sm[1024];
    int t = threadIdx.x;
    int v = (t < NB) ? partial[t] : 0;
    sm[t] = v;
    __syncthreads();
    for (int off = 1; off < 1024; off <<= 1) {
        int u = (t >= off) ? sm[t - off] : 0;
        __syncthreads();
        sm[t] += u;
        __syncthreads();
    }
    if (t < NB) partial[t] = sm[t] - v;  // exclusive
    if (t == 0) rowptr[N] = E;
}

// Phase C: block b scans its 1024-chunk in LDS, adds partial[b], writes rowptr+cursor
__global__ void k_scan_final(const int* __restrict__ deg, const int* __restrict__ partial,
                             int* __restrict__ rowptr, int* __restrict__ cursor, int N) {
    __shared__ int sm[1024];
    int t = threadIdx.x;
    int i = blockIdx.x * 1024 + t;
    int v = (i < N) ? deg[i] : 0;
    sm[t] = v;
    __syncthreads();
    for (int off = 1; off < 1024; off <<= 1) {
        int u = (t >= off) ? sm[t - off] : 0;
        __syncthreads();
        sm[t] += u;
        __syncthreads();
    }
    if (i < N) {
        int excl = sm[t] - v + partial[blockIdx.x];
        rowptr[i] = excl;
        cursor[i] = excl;
    }
}

__global__ void k_scatter(const int* __restrict__ ei, int* __restrict__ cursor,
                          int* __restrict__ ssrc, int E) {
    int e = blockIdx.x * blockDim.x + threadIdx.x;
    if (e >= E) return;
    int s = ei[e], d = ei[E + e];
    int pos = atomicAdd(&cursor[d], 1);
    ssrc[pos] = s;
}

// ---------------- precompute tiny projections ----------------
// pbuf layout (32 floats): [0..7]=Ps(d=0), [8..15]=Ps(d=1), [16..23]=Pd(d=0), [24..31]=Pd(d=1)
// Ps[d][h] = sum_c W1[d*128 + h*16 + c] * att_src1[h*16 + c]   (likewise Pd with att_dst1)
__global__ void k_precompute(const float* __restrict__ W1, const float* __restrict__ att_src,
                             const float* __restrict__ att_dst, float* __restrict__ pbuf) {
    int t = threadIdx.x;  // 32 threads: t = which*16 + h*2 + d  -> simpler: t<16 src, t>=16 dst
    if (t >= 32) return;
    int which = t >> 4;          // 0 = src, 1 = dst
    int hd = t & 15;             // h*2+d
    int h = hd >> 1, d = hd & 1;
    const float* att = which ? att_dst : att_src;
    float s = 0.0f;
#pragma unroll
    for (int c = 0; c < 16; ++c) s += W1[d * 128 + h * 16 + c] * att[h * 16 + c];
    pbuf[which * 16 + d * 8 + h] = s;
}

// ---------------- fused layer 1 + transform 2 ----------------
// thread = (node n, head h), 8 consecutive lanes per node.
// Online softmax over rank-2 features: track l, Sx0, Sx1 only.
// Epilogue: 16 channels -> partial h2[4], shfl-reduce over 8 head lanes,
// lane h==0 writes h2[n,:4], a2s[n], a2d[n].
__global__ void k_gather1(const int* __restrict__ rowptr, const int* __restrict__ ssrc,
                          const float* __restrict__ x, const float* __restrict__ pbuf,
                          const float* __restrict__ W1, const float* __restrict__ b1,
                          const float* __restrict__ W2, const float* __restrict__ att_src2,
                          const float* __restrict__ att_dst2, float* __restrict__ h2,
                          float* __restrict__ a2s, float* __restrict__ a2d, int N) {
    int t = blockIdx.x * blockDim.x + threadIdx.x;
    int n = t >> 3, h = t & 7;
    bool active = (n < N);
    float Ps0 = pbuf[h], Ps1 = pbuf[8 + h];
    float Pd0 = pbuf[16 + h], Pd1 = pbuf[24 + h];
    float m = -INFINITY, l = 0.0f, sx0 = 0.0f, sx1 = 0.0f;
    if (active) {
        float2 xn = ((const float2*)x)[n];
        float ad = xn.x * Pd0 + xn.y * Pd1;
        int start = rowptr[n], end = rowptr[n + 1];
        for (int j = start; j < end; ++j) {
            int src = ssrc[j];
            float2 xs = ((const float2*)x)[src];
            float e = leaky(xs.x * Ps0 + xs.y * Ps1 + ad);
            if (e > m) {
                float sc = __expf(m - e);  // m=-inf -> 0
                l *= sc; sx0 *= sc; sx1 *= sc;
                m = e;
            }
            float p = __expf(e - m);
            l += p;
            sx0 += p * xs.x;
            sx1 += p * xs.y;
        }
    }
    float inv = 1.0f / (l + kEps);
    float sX0 = sx0 * inv, sX1 = sx1 * inv;
    float h0 = 0.f, h1v = 0.f, h2v = 0.f, h3 = 0.f;
#pragma unroll
    for (int c = 0; c < 16; ++c) {
        int col = h * 16 + c;
        float o = fmaxf(W1[col] * sX0 + W1[128 + col] * sX1 + b1[col], 0.0f);
        h0 += o * W2[col * 4 + 0];
        h1v += o * W2[col * 4 + 1];
        h2v += o * W2[col * 4 + 2];
        h3 += o * W2[col * 4 + 3];
    }
#pragma unroll
    for (int off = 1; off < 8; off <<= 1) {
        h0 += __shfl_xor(h0, off);
        h1v += __shfl_xor(h1v, off);
        h2v += __shfl_xor(h2v, off);
        h3 += __shfl_xor(h3, off);
    }
    if (active && h == 0) {
        ((float4*)h2)[n] = make_float4(h0, h1v, h2v, h3);
        a2s[n] = h0 * att_src2[0] + h1v * att_src2[1] + h2v * att_src2[2] + h3 * att_src2[3];
        a2d[n] = h0 * att_dst2[0] + h1v * att_dst2[1] + h2v * att_dst2[2] + h3 * att_dst2[3];
    }
}

// ---------------- layer 2 gather + log_softmax ----------------
__global__ void k_gather2_out(const int* __restrict__ rowptr, const int* __restrict__ ssrc,
                              const float* __restrict__ a2s, const float* __restrict__ a2d,
                              const float* __restrict__ h2, const float* __restrict__ b2,
                              float* __restrict__ out, int N) {
    int n = blockIdx.x * blockDim.x + threadIdx.x;
    if (n >= N) return;
    int start = rowptr[n], end = rowptr[n + 1];
    float ad = a2d[n];
    float m = -INFINITY, l = 0.0f;
    float4 acc = make_float4(0.f, 0.f, 0.f, 0.f);
    for (int j = start; j < end; ++j) {
        int src = ssrc[j];
        float e = leaky(a2s[src] + ad);
        float4 hv = ((const float4*)h2)[src];
        if (e > m) {
            float sc = __expf(m - e);
            acc.x *= sc; acc.y *= sc; acc.z *= sc; acc.w *= sc;
            l *= sc;
            m = e;
        }
        float p = __expf(e - m);
        l += p;
        acc.x += p * hv.x; acc.y += p * hv.y; acc.z += p * hv.z; acc.w += p * hv.w;
    }
    float inv = 1.0f / (l + kEps);
    float4 v = make_float4(acc.x * inv + b2[0], acc.y * inv + b2[1],
                           acc.z * inv + b2[2], acc.w * inv + b2[3]);
    float mx = fmaxf(fmaxf(v.x, v.y), fmaxf(v.z, v.w));
    float sum = __expf(v.x - mx) + __expf(v.y - mx) + __expf(v.z - mx) + __expf(v.w - mx);
    float lse = mx + logf(sum);
    ((float4*)out)[n] = make_float4(v.x - lse, v.y - lse, v.z - lse, v.w - lse);
}

extern "C" void kernel_launch(void* const* d_in, const int* in_sizes, int n_in,
                              void* d_out, int out_size, void* d_ws, size_t ws_size,
                              hipStream_t stream) {
    const float* x        = (const float*)d_in[0];
    const int*   ei       = (const int*)d_in[1];
    const float* W1       = (const float*)d_in[2];
    const float* att_src1 = (const float*)d_in[3];
    const float* att_dst1 = (const float*)d_in[4];
    const float* b1       = (const float*)d_in[5];
    const float* W2       = (const float*)d_in[6];
    const float* att_src2 = (const float*)d_in[7];
    const float* att_dst2 = (const float*)d_in[8];
    const float* b2       = (const float*)d_in[9];

    const int N = in_sizes[0] / 2;     // x is [N,2]
    const int E = in_sizes[1] / 2;     // edge_index is [2,E]
    const int NB = (N + 1023) / 1024;  // scan blocks (<= 1024)

    // ---- workspace layout ----
    int* deg     = (int*)d_ws;        // N (doubles as cursor)
    int* rowptr  = deg + N;           // N+1 (pad to N+4)
    int* ssrc    = rowptr + N + 4;    // E
    int* partial = ssrc + E;          // NB (pad 1024)
    float* pbuf  = (float*)(partial + 1024);  // 32
    float* h2    = pbuf + 32;         // N*4
    float* a2s   = h2 + (size_t)N * 4;  // N
    float* a2d   = a2s + N;           // N

    const int T = 256;

    // CSR build (by destination)
    k_zero<<<256, T, 0, stream>>>(deg, N);
    k_hist<<<(E + T - 1) / T, T, 0, stream>>>(ei, deg, E);
    k_scan_reduce<<<NB, 1024, 0, stream>>>(deg, partial, N);
    k_scan_top<<<1, 1024, 0, stream>>>(partial, rowptr, NB, N, E);
    k_scan_final<<<NB, 1024, 0, stream>>>(deg, partial, rowptr, deg /*cursor*/, N);
    k_scatter<<<(E + T - 1) / T, T, 0, stream>>>(ei, deg /*cursor*/, ssrc, E);

    // tiny projections
    k_precompute<<<1, 64, 0, stream>>>(W1, att_src1, att_dst1, pbuf);

    // fused layer 1 + transform 2
    k_gather1<<<(N * 8 + T - 1) / T, T, 0, stream>>>(rowptr, ssrc, x, pbuf, W1, b1, W2,
                                                     att_src2, att_dst2, h2, a2s, a2d, N);

    // layer 2 gather + log_softmax
    k_gather2_out<<<(N + T - 1) / T, T, 0, stream>>>(rowptr, ssrc, a2s, a2d, h2, b2,
                                                     (float*)d_out, N);
}